// Round 9
// baseline (18.460 us; speedup 1.0000x reference)
//
#include <hip/hip_runtime.h>

// ChannelEstimator, two-kernel split:
//   A) pilot LS: one pilot per thread, pure read-stream (Y stride-64B lines,
//      coalesced Xp/weights), H[P+1] (incl. extrapolated endpoint) -> d_ws.
//   B) interpolation: coalesced H load from d_ws -> LDS, then pure
//      nontemporal-float4 store stream (R7 structure).
// Rationale: every fused variant (R3-R8, 14.8-17.2us) serializes a
// gather-latency chain in front of each block's store stream. Splitting makes
// both kernels clean single-phase streams; H round-trip is +4 MB, L3-hot.

typedef float f32x4 __attribute__((ext_vector_type(4)));

constexpr int NT      = 128;
constexpr int PAIRS   = 8;                 // float4 stores per thread (kernel B)
constexpr int CHUNK   = NT * PAIRS * 2;    // 2048 subcarriers per block
constexpr int SPACING = 16;
constexpr int NTA     = 256;               // kernel A block size

// ---- kernel A: per-pilot weighted LS, H -> workspace ----
__global__ __launch_bounds__(NTA) void pilot_kernel(
    const float* __restrict__ Y_real, const float* __restrict__ Y_imag,
    const float* __restrict__ Xp_real, const float* __restrict__ Xp_imag,
    const float* __restrict__ weights,
    float* __restrict__ Hr, float* __restrict__ Hi, int Nfft, int P)
{
    const int k = blockIdx.x * NTA + threadIdx.x;
    if (k >= P) return;

    auto ls = [&](int kk, float& hr, float& hi) {
        float yr = Y_real[(size_t)kk * SPACING], yi = Y_imag[(size_t)kk * SPACING];
        float xr = Xp_real[kk],                  xi = Xp_imag[kk];
        float inv = 1.0f / (xr * xr + xi * xi);
        float wk  = weights[kk];
        hr = (yr * xr + yi * xi) * inv * wk;
        hi = (yi * xr - yr * xi) * inv * wk;
    };

    float hr, hi; ls(k, hr, hi);
    Hr[k] = hr; Hi[k] = hi;

    if (k == P - 1) {
        // extrapolated endpoint at subcarrier Nfft-1 -> H[P]
        float hr2, hi2; ls(P - 2, hr2, hi2);
        float l1 = (float)((P - 1) * SPACING);
        float l2 = (float)((P - 2) * SPACING);
        float inv_dx = 1.0f / (l1 - l2);
        float dend   = (float)(Nfft - 1) - l1;
        Hr[P] = hr + (hr - hr2) * inv_dx * dend;
        Hi[P] = hi + (hi - hi2) * inv_dx * dend;
    }
}

// ---- kernel B: linear interpolation, NT float4 store stream ----
__global__ __launch_bounds__(NT) void interp_kernel(
    const float* __restrict__ Hr, const float* __restrict__ Hi,
    const float* __restrict__ alpha_p, const float* __restrict__ beta_p,
    const float* __restrict__ gamma_p,
    f32x4* __restrict__ out4, int Nfft, int P)
{
    constexpr int NP = CHUNK / SPACING;    // 128 pilots per block
    __shared__ float sHr [NP + 1];
    __shared__ float sHi [NP + 1];

    const int t    = threadIdx.x;
    const int p0   = blockIdx.x * NP;
    const int base = blockIdx.x * CHUNK;

    const float a = *alpha_p;
    const float b = *beta_p;
    const float g = *gamma_p;

    // coalesced H load (L3-hot: written by pilot_kernel one dispatch earlier)
    sHr[t] = Hr[p0 + t];
    sHi[t] = Hi[p0 + t];
    if (t == 0) {
        sHr[NP] = Hr[p0 + NP];     // H has P+1 valid entries
        sHi[NP] = Hi[p0 + NP];
    }
    __syncthreads();

    // widths: SPACING everywhere except extrapolated last segment (width 15)
    const bool lastBlock = (p0 + NP >= P);

    #pragma unroll
    for (int j = 0; j < PAIRS; ++j) {
        int i0 = base + j * (NT * 2) + 2 * t;       // even subcarrier
        int lp = (i0 >> 4) - p0;                    // segment for i0 and i0+1
        float inv = (lastBlock && lp == NP - 1)
                        ? (1.0f / (float)(SPACING - 1))
                        : (1.0f / (float)SPACING);
        float X0  = (float)((p0 + lp) * SPACING);
        float df0 = ((float)i0 - X0) * inv;
        float hr0 = sHr[lp], hr1 = sHr[lp + 1];
        float hi0 = sHi[lp], hi1 = sHi[lp + 1];
        float rr = a * hr1 + b * hr0;
        float ii = a * hi1 + b * hi0;
        f32x4 o;
        o.x = rr + g * df0;
        o.y = ii;
        o.z = rr + g * (df0 + inv);
        o.w = ii;
        __builtin_nontemporal_store(o, &out4[(base >> 1) + j * NT + t]);
    }
}

extern "C" void kernel_launch(void* const* d_in, const int* in_sizes, int n_in,
                              void* d_out, int out_size, void* d_ws, size_t ws_size,
                              hipStream_t stream) {
    const float* Yr = (const float*)d_in[0];
    const float* Yi = (const float*)d_in[1];
    const float* Xr = (const float*)d_in[2];
    const float* Xi = (const float*)d_in[3];
    const float* w  = (const float*)d_in[4];
    const float* al = (const float*)d_in[5];
    const float* be = (const float*)d_in[6];
    const float* ga = (const float*)d_in[7];
    const int Nfft = in_sizes[0];   // 4194304
    const int P    = in_sizes[2];   // 262144

    float* Hr = (float*)d_ws;                      // P+1 floats
    float* Hi = Hr + (P + 1);

    pilot_kernel<<<(P + NTA - 1) / NTA, NTA, 0, stream>>>(
        Yr, Yi, Xr, Xi, w, Hr, Hi, Nfft, P);

    const int grid = (Nfft + CHUNK - 1) / CHUNK;   // 2048 blocks
    interp_kernel<<<grid, NT, 0, stream>>>(
        Hr, Hi, al, be, ga, (f32x4*)d_out, Nfft, P);
}

// Round 10
// 14.907 us; speedup vs baseline: 1.2384x; 1.2384x over previous
//
#include <hip/hip_runtime.h>

// ChannelEstimator: per-pilot complex LS + endpoint extrapolation + trainable
// linear interpolation, fused in one kernel.
//
// R10 = revert to R7, the session's best (14.8 us). Structure:
//  - NT=128, CHUNK=2048 (2048 blocks, 8/CU), nontemporal float4 stores
//    (beat cached stores 15.5 vs 17.2 -- no RFO/cache churn).
//  - arithmetic loc = 16*k (spacing-16 grid; the i>>4 segment map assumes it),
//    so pilot_pos is never read -- no dependent address chains anywhere.
// Falsified alternatives: NT=64 single-wave blocks (16.6), coalesced-span Y
// reads (15.8), cached stores (17.2), 4096-block grid (15.4), two-kernel
// split (18.5). Remaining time = traffic floor (~69 MB ~= 10.4 us at the
// demonstrated 6.6 TB/s) + read ramp + fixed graph-replay overhead.

typedef float f32x4 __attribute__((ext_vector_type(4)));

constexpr int NT      = 128;
constexpr int PAIRS   = 8;                 // float4 stores per thread
constexpr int CHUNK   = NT * PAIRS * 2;    // 2048 subcarriers per block
constexpr int SPACING = 16;

__global__ __launch_bounds__(NT) void ce_kernel(
    const float* __restrict__ Y_real, const float* __restrict__ Y_imag,
    const float* __restrict__ Xp_real, const float* __restrict__ Xp_imag,
    const float* __restrict__ weights,
    const float* __restrict__ alpha_p, const float* __restrict__ beta_p,
    const float* __restrict__ gamma_p,
    f32x4* __restrict__ out4, int Nfft, int P)
{
    constexpr int NP = CHUNK / SPACING;    // pilots per block = 128 == NT
    __shared__ float sHr [NP + 1];
    __shared__ float sHi [NP + 1];

    const int t    = threadIdx.x;
    const int p0   = blockIdx.x * NP;      // first pilot index of this block
    const int base = blockIdx.x * CHUNK;   // first subcarrier of this block

    const float a = *alpha_p;
    const float b = *beta_p;
    const float g = *gamma_p;

    // weighted LS at pilot kk (spacing-16 grid addressing, no indirection)
    auto ls = [&](int kk, float& hr, float& hi) {
        float yr = Y_real[(size_t)kk * SPACING], yi = Y_imag[(size_t)kk * SPACING];
        float xr = Xp_real[kk],                  xi = Xp_imag[kk];
        float inv = 1.0f / (xr * xr + xi * xi);
        float wk  = weights[kk];
        hr = (yr * xr + yi * xi) * inv * wk;
        hi = (yi * xr - yr * xi) * inv * wk;
    };

    // ---- phase 1: 128 pilots + boundary pilot into LDS ----
    {
        const int k = p0 + t;              // < P (grid covers pilots exactly)
        float hr, hi; ls(k, hr, hi);
        sHr[t] = hr; sHi[t] = hi;
    }
    if (t == 0) {
        int ke = p0 + NP;
        if (ke < P) {
            float hr, hi; ls(ke, hr, hi);
            sHr[NP] = hr; sHi[NP] = hi;
        } else {
            // extended endpoint at Nfft-1: linear extrapolation from last two pilots
            float hr1, hi1, hr2, hi2;
            ls(P - 1, hr1, hi1);
            ls(P - 2, hr2, hi2);
            float l1 = (float)((P - 1) * SPACING);
            float l2 = (float)((P - 2) * SPACING);
            float inv_dx = 1.0f / (l1 - l2);
            float dend   = (float)(Nfft - 1) - l1;
            sHr[NP] = hr1 + (hr1 - hr2) * inv_dx * dend;
            sHi[NP] = hi1 + (hi1 - hi2) * inv_dx * dend;
        }
    }
    __syncthreads();

    // segment widths: SPACING everywhere except the extrapolated last segment
    // [Nfft-16, Nfft-1] (width 15), which lives in the last block only.
    const bool lastBlock = (p0 + NP >= P);

    // ---- phase 2: interpolate, 2 subcarriers per nontemporal float4 ----
    #pragma unroll
    for (int j = 0; j < PAIRS; ++j) {
        int i0 = base + j * (NT * 2) + 2 * t;       // even subcarrier
        int lp = (i0 >> 4) - p0;                    // segment for i0 and i0+1
        float inv = (lastBlock && lp == NP - 1)
                        ? (1.0f / (float)(SPACING - 1))   // width 15
                        : (1.0f / (float)SPACING);        // width 16
        float X0  = (float)((p0 + lp) * SPACING);
        float df0 = ((float)i0 - X0) * inv;
        float hr0 = sHr[lp], hr1 = sHr[lp + 1];
        float hi0 = sHi[lp], hi1 = sHi[lp + 1];
        float rr = a * hr1 + b * hr0;
        float ii = a * hi1 + b * hi0;
        f32x4 o;
        o.x = rr + g * df0;
        o.y = ii;
        o.z = rr + g * (df0 + inv);
        o.w = ii;
        __builtin_nontemporal_store(o, &out4[(base >> 1) + j * NT + t]);
    }
}

extern "C" void kernel_launch(void* const* d_in, const int* in_sizes, int n_in,
                              void* d_out, int out_size, void* d_ws, size_t ws_size,
                              hipStream_t stream) {
    const float* Yr = (const float*)d_in[0];
    const float* Yi = (const float*)d_in[1];
    const float* Xr = (const float*)d_in[2];
    const float* Xi = (const float*)d_in[3];
    const float* w  = (const float*)d_in[4];
    const float* al = (const float*)d_in[5];
    const float* be = (const float*)d_in[6];
    const float* ga = (const float*)d_in[7];
    const int Nfft = in_sizes[0];   // 4194304
    const int P    = in_sizes[2];   // 262144

    const int grid = (Nfft + CHUNK - 1) / CHUNK;   // 2048 blocks
    ce_kernel<<<grid, NT, 0, stream>>>(Yr, Yi, Xr, Xi, w, al, be, ga,
                                       (f32x4*)d_out, Nfft, P);
}